// Round 2
// baseline (381.142 us; speedup 1.0000x reference)
//
#include <hip/hip_runtime.h>
#include <math.h>

namespace {

constexpr int N_ = 1024;
constexpr int M_ = 1024;
constexpr int C_ = 64;

__device__ __forceinline__ float sig(float x) { return 1.0f / (1.0f + expf(-x)); }

// ---------------------------------------------------------------------------
// Kernel 1: pre-MLP (3 layers) + projection through post_w1.
// rows 0..1023 = step_x, rows 1024..2047 = state_x.
// U[row][c] = ( mlp3_pre(x_row) @ post_w1 )[c]      (NO post_b1 here)
// ---------------------------------------------------------------------------
__global__ __launch_bounds__(256) void pre_kernel(
    const float* __restrict__ step_x, const float* __restrict__ state_x,
    const float* __restrict__ w1, const float* __restrict__ b1,
    const float* __restrict__ w2, const float* __restrict__ b2,
    const float* __restrict__ w3, const float* __restrict__ b3,
    const float* __restrict__ pw1,
    float* __restrict__ U)
{
    __shared__ float XA[32][C_ + 1];
    __shared__ float XB[32][C_ + 1];
    __shared__ float W[C_ * C_];
    __shared__ float Bv[C_];

    const int t = threadIdx.x;
    const int c = t & 63;
    const int rg = t >> 6;              // 0..3, 8 rows each
    const int rbase = blockIdx.x * 32;

    const float* src_g = (rbase < N_) ? (step_x + (size_t)rbase * C_)
                                      : (state_x + (size_t)(rbase - N_) * C_);
    for (int e = t; e < 32 * 16; e += 256) {
        int row = e >> 4, k4 = (e & 15) << 2;
        float4 v = *reinterpret_cast<const float4*>(src_g + row * C_ + k4);
        XA[row][k4 + 0] = v.x; XA[row][k4 + 1] = v.y;
        XA[row][k4 + 2] = v.z; XA[row][k4 + 3] = v.w;
    }

    const float* Ws[4] = {w1, w2, w3, pw1};
    const float* Bs[4] = {b1, b2, b3, nullptr};

    float (*sA)[C_ + 1] = XA;
    float (*sB)[C_ + 1] = XB;

    for (int layer = 0; layer < 4; ++layer) {
        __syncthreads();  // protect W overwrite + sA writes from prev layer
        for (int e = t; e < C_ * C_ / 4; e += 256)
            reinterpret_cast<float4*>(W)[e] =
                reinterpret_cast<const float4*>(Ws[layer])[e];
        if (t < C_) Bv[t] = (layer == 3) ? 0.0f : Bs[layer][t];
        __syncthreads();
        const bool relu = (layer < 2);
        #pragma unroll
        for (int q = 0; q < 8; ++q) {
            const int row = rg * 8 + q;
            float acc = Bv[c];
            #pragma unroll 8
            for (int k = 0; k < C_; ++k)
                acc = fmaf(sA[row][k], W[k * C_ + c], acc);
            sB[row][c] = relu ? fmaxf(acc, 0.0f) : acc;
        }
        float (*tmp)[C_ + 1] = sA; sA = sB; sB = tmp;
    }
    // result rows are in sA; each thread reads back only its own writes
    #pragma unroll
    for (int q = 0; q < 8; ++q) {
        const int row = rg * 8 + q;
        U[(size_t)(rbase + row) * C_ + c] = sA[row][c];
    }
}

// ---------------------------------------------------------------------------
// Kernel 2: pairwise post-MLP.  z=0: ss (V=U step rows), z=1: st (V=state rows)
// logits[(i*1024+j)*2 + {0,1}]
// 16x16 (i,j) tile, 256 threads; thread = 4 ii x 2 jj pairs x 8 channels.
// ---------------------------------------------------------------------------
__global__ __launch_bounds__(256) void pair_kernel(
    const float* __restrict__ U,
    const float* __restrict__ pb1,
    const float* __restrict__ pw2, const float* __restrict__ pb2,
    const float* __restrict__ pw3, const float* __restrict__ pb3,
    float* __restrict__ out)
{
    __shared__ float SU[16][C_ + 1];   // +1 pad: avoid 8-way bank conflict
    __shared__ float SV[16][C_ + 1];
    __shared__ float W2[C_ * C_];
    __shared__ float W3[C_][2];
    __shared__ float OUTT[256][2];

    const int t = threadIdx.x;
    const int zz = blockIdx.z;
    const int ibase = blockIdx.y * 16;
    const int jbase = blockIdx.x * 16;

    const float* Urow = U + (size_t)ibase * C_;
    const float* Vrow = U + (size_t)(zz ? N_ : 0) * C_ + (size_t)jbase * C_;
    float* obase = out + (size_t)zz * ((size_t)2 * N_ * M_);

    {   // stage SU (raw) and SV (+post_b1): 256 float4 each, one per thread
        int row = t >> 4, k4 = (t & 15) << 2;
        float4 a = *reinterpret_cast<const float4*>(Urow + row * C_ + k4);
        SU[row][k4 + 0] = a.x; SU[row][k4 + 1] = a.y;
        SU[row][k4 + 2] = a.z; SU[row][k4 + 3] = a.w;
        float4 b = *reinterpret_cast<const float4*>(Vrow + row * C_ + k4);
        float4 bb = *reinterpret_cast<const float4*>(pb1 + k4);
        SV[row][k4 + 0] = b.x + bb.x; SV[row][k4 + 1] = b.y + bb.y;
        SV[row][k4 + 2] = b.z + bb.z; SV[row][k4 + 3] = b.w + bb.w;
    }
    for (int e = t; e < C_ * C_ / 4; e += 256)
        reinterpret_cast<float4*>(W2)[e] = reinterpret_cast<const float4*>(pw2)[e];
    if (t < 128) W3[t >> 1][t & 1] = pw3[t];
    __syncthreads();

    const int cg = t & 7;               // channel group lane (8 lanes/group)
    const int pg = t >> 3;              // pair group 0..31
    const int ii0 = (pg >> 3) << 2;     // 0,4,8,12
    const int jj0 = (pg & 7) << 1;      // 0,2,..,14
    const int c0 = cg << 3;

    float acc[4][2][8];
    #pragma unroll
    for (int r = 0; r < 4; ++r)
        #pragma unroll
        for (int s = 0; s < 2; ++s)
            #pragma unroll
            for (int q = 0; q < 8; ++q) acc[r][s][q] = 0.0f;

    #pragma unroll 4
    for (int k = 0; k < C_; ++k) {
        float su[4], sv[2];
        #pragma unroll
        for (int r = 0; r < 4; ++r) su[r] = SU[ii0 + r][k];
        sv[0] = SV[jj0][k]; sv[1] = SV[jj0 + 1][k];
        float4 wA = *reinterpret_cast<const float4*>(&W2[k * C_ + c0]);
        float4 wB = *reinterpret_cast<const float4*>(&W2[k * C_ + c0 + 4]);
        float wv[8] = {wA.x, wA.y, wA.z, wA.w, wB.x, wB.y, wB.z, wB.w};
        #pragma unroll
        for (int r = 0; r < 4; ++r) {
            #pragma unroll
            for (int s = 0; s < 2; ++s) {
                float a = fmaxf(su[r] + sv[s], 0.0f);   // h1 = relu(U_i+V_j+b1)
                #pragma unroll
                for (int q = 0; q < 8; ++q)
                    acc[r][s][q] = fmaf(a, wv[q], acc[r][s][q]);
            }
        }
    }

    // epilogue: h2 = relu(acc + b2); out = h2 @ w3 + b3 (reduce over 8 cg lanes)
    float4 bA = *reinterpret_cast<const float4*>(pb2 + c0);
    float4 bB = *reinterpret_cast<const float4*>(pb2 + c0 + 4);
    float b2v[8] = {bA.x, bA.y, bA.z, bA.w, bB.x, bB.y, bB.z, bB.w};
    float w30[8], w31[8];
    #pragma unroll
    for (int q = 0; q < 8; ++q) { w30[q] = W3[c0 + q][0]; w31[q] = W3[c0 + q][1]; }
    const float ob0 = pb3[0], ob1 = pb3[1];

    #pragma unroll
    for (int r = 0; r < 4; ++r) {
        #pragma unroll
        for (int s = 0; s < 2; ++s) {
            float p0 = 0.0f, p1 = 0.0f;
            #pragma unroll
            for (int q = 0; q < 8; ++q) {
                float h = fmaxf(acc[r][s][q] + b2v[q], 0.0f);
                p0 = fmaf(h, w30[q], p0);
                p1 = fmaf(h, w31[q], p1);
            }
            #pragma unroll
            for (int m = 1; m < 8; m <<= 1) {
                p0 += __shfl_xor(p0, m);
                p1 += __shfl_xor(p1, m);
            }
            if (cg == 0) {
                int p = (ii0 + r) * 16 + (jj0 + s);
                OUTT[p][0] = p0 + ob0;
                OUTT[p][1] = p1 + ob1;
            }
        }
    }
    __syncthreads();
    {   // coalesced write: thread t writes pair p=t as float2
        int i = ibase + (t >> 4), j = jbase + (t & 15);
        float2 v = *reinterpret_cast<float2*>(&OUTT[t][0]);
        *reinterpret_cast<float2*>(obase + ((size_t)i * M_ + j) * 2) = v;
    }
}

// ---------------------------------------------------------------------------
// Kernel 3: col_arg[j] = argmax_i sigmoid(Lst[i][j][0])  (first-max semantics)
// block = 32 columns x 8 i-groups
// ---------------------------------------------------------------------------
__global__ __launch_bounds__(256) void colmax_kernel(
    const float* __restrict__ Lst, int* __restrict__ col_arg)
{
    __shared__ float svv[256];
    __shared__ int sii[256];
    const int t = threadIdx.x;
    const int jt = t & 31, ig = t >> 5;
    const int j = blockIdx.x * 32 + jt;
    float best = -INFINITY; int bidx = 0x7fffffff;
    for (int i = ig; i < N_; i += 8) {          // ascending i, strict > => first max
        float v = sig(Lst[((size_t)i * M_ + j) * 2]);
        if (v > best) { best = v; bidx = i; }
    }
    svv[t] = best; sii[t] = bidx;
    for (int h = 4; h > 0; h >>= 1) {
        __syncthreads();
        if (ig < h) {
            float ov = svv[t + h * 32]; int oi = sii[t + h * 32];
            if (ov > svv[t] || (ov == svv[t] && oi < sii[t])) { svv[t] = ov; sii[t] = oi; }
        }
    }
    __syncthreads();
    if (ig == 0) col_arg[j] = sii[t];
}

// ---------------------------------------------------------------------------
// Kernel 4: row_arg[i] = argmax_j s1[i][j], s1 = match masked by col_arg[j]==i
// block = 8 rows x 32 lanes
// ---------------------------------------------------------------------------
__global__ __launch_bounds__(256) void rowmax_kernel(
    const float* __restrict__ Lst, const int* __restrict__ col_arg,
    int* __restrict__ row_arg)
{
    __shared__ int ca[M_];
    const int t = threadIdx.x;
    for (int e = t; e < M_; e += 256) ca[e] = col_arg[e];
    __syncthreads();
    const int lr = t >> 5, jt = t & 31;
    const int i = blockIdx.x * 8 + lr;
    float best = -INFINITY; int bidx = 0x7fffffff;
    for (int j = jt; j < M_; j += 32) {
        if (ca[j] == i) {
            float v = sig(Lst[((size_t)i * M_ + j) * 2]);
            if (v > best) { best = v; bidx = j; }
        }
    }
    #pragma unroll
    for (int m = 1; m < 32; m <<= 1) {
        float ov = __shfl_xor(best, m);
        int oi = __shfl_xor(bidx, m);
        if (ov > best || (ov == best && oi < bidx)) { best = ov; bidx = oi; }
    }
    if (jt == 0) row_arg[i] = (best == -INFINITY) ? 0 : bidx;
}

// ---------------------------------------------------------------------------
// Kernel 5: matched[i][j] = (col_arg[j]==i && row_arg[i]==j) ? sigmoid : 0
// ---------------------------------------------------------------------------
__global__ __launch_bounds__(256) void fill_kernel(
    const float* __restrict__ Lst, const int* __restrict__ col_arg,
    const int* __restrict__ row_arg, float* __restrict__ matched)
{
    const int i = blockIdx.x;
    const int ra = row_arg[i];
    for (int j = threadIdx.x; j < M_; j += 256) {
        float v = 0.0f;
        if (ra == j && col_arg[j] == i)
            v = sig(Lst[((size_t)i * M_ + j) * 2]);
        matched[(size_t)i * M_ + j] = v;
    }
}

} // namespace

extern "C" void kernel_launch(void* const* d_in, const int* in_sizes, int n_in,
                              void* d_out, int out_size, void* d_ws, size_t ws_size,
                              hipStream_t stream)
{
    const float* step_x  = (const float*)d_in[0];
    const float* state_x = (const float*)d_in[1];
    const float* pre_w1  = (const float*)d_in[2];
    const float* pre_b1  = (const float*)d_in[3];
    const float* pre_w2  = (const float*)d_in[4];
    const float* pre_b2  = (const float*)d_in[5];
    const float* pre_w3  = (const float*)d_in[6];
    const float* pre_b3  = (const float*)d_in[7];
    const float* post_w1 = (const float*)d_in[8];
    const float* post_b1 = (const float*)d_in[9];
    const float* post_w2 = (const float*)d_in[10];
    const float* post_b2 = (const float*)d_in[11];
    const float* post_w3 = (const float*)d_in[12];
    const float* post_b3 = (const float*)d_in[13];

    float* out     = (float*)d_out;
    float* Lst     = out + (size_t)2 * N_ * M_;
    float* matched = out + (size_t)4 * N_ * M_;

    float* U       = (float*)d_ws;                          // 2048*64 f32
    int*   col_arg = (int*)((char*)d_ws + (size_t)2048 * 64 * 4);
    int*   row_arg = col_arg + 1024;

    hipLaunchKernelGGL(pre_kernel, dim3(64), dim3(256), 0, stream,
        step_x, state_x, pre_w1, pre_b1, pre_w2, pre_b2, pre_w3, pre_b3,
        post_w1, U);
    hipLaunchKernelGGL(pair_kernel, dim3(64, 64, 2), dim3(256), 0, stream,
        U, post_b1, post_w2, post_b2, post_w3, post_b3, out);
    hipLaunchKernelGGL(colmax_kernel, dim3(32), dim3(256), 0, stream,
        Lst, col_arg);
    hipLaunchKernelGGL(rowmax_kernel, dim3(128), dim3(256), 0, stream,
        Lst, col_arg, row_arg);
    hipLaunchKernelGGL(fill_kernel, dim3(1024), dim3(256), 0, stream,
        Lst, col_arg, row_arg, matched);
}

// Round 3
// 213.793 us; speedup vs baseline: 1.7828x; 1.7828x over previous
//
#include <hip/hip_runtime.h>
#include <math.h>

namespace {

constexpr int N_ = 1024;
constexpr int M_ = 1024;
constexpr int C_ = 64;

typedef _Float16 f16x8 __attribute__((ext_vector_type(8)));
typedef float f32x4 __attribute__((ext_vector_type(4)));
static_assert(sizeof(f16x8) == 16, "f16x8 must be 4 VGPRs");

__device__ __forceinline__ float sig(float x) { return 1.0f / (1.0f + expf(-x)); }

__device__ __forceinline__ unsigned long long packkey(float v, unsigned idx) {
    // v > 0 always (sigmoid); bigger val wins, then smaller idx wins.
    return ((unsigned long long)__float_as_uint(v) << 32) | (unsigned)(0xFFFFFFFFu - idx);
}

// ---------------------------------------------------------------------------
// Kernel 1: pre-MLP (3 layers) + projection through post_w1. (unchanged, proven)
// rows 0..1023 = step_x, rows 1024..2047 = state_x.
// U[row][c] = ( mlp3_pre(x_row) @ post_w1 )[c]      (NO post_b1 here)
// ---------------------------------------------------------------------------
__global__ __launch_bounds__(256) void pre_kernel(
    const float* __restrict__ step_x, const float* __restrict__ state_x,
    const float* __restrict__ w1, const float* __restrict__ b1,
    const float* __restrict__ w2, const float* __restrict__ b2,
    const float* __restrict__ w3, const float* __restrict__ b3,
    const float* __restrict__ pw1,
    float* __restrict__ U)
{
    __shared__ float XA[32][C_ + 1];
    __shared__ float XB[32][C_ + 1];
    __shared__ float W[C_ * C_];
    __shared__ float Bv[C_];

    const int t = threadIdx.x;
    const int c = t & 63;
    const int rg = t >> 6;
    const int rbase = blockIdx.x * 32;

    const float* src_g = (rbase < N_) ? (step_x + (size_t)rbase * C_)
                                      : (state_x + (size_t)(rbase - N_) * C_);
    for (int e = t; e < 32 * 16; e += 256) {
        int row = e >> 4, k4 = (e & 15) << 2;
        float4 v = *reinterpret_cast<const float4*>(src_g + row * C_ + k4);
        XA[row][k4 + 0] = v.x; XA[row][k4 + 1] = v.y;
        XA[row][k4 + 2] = v.z; XA[row][k4 + 3] = v.w;
    }

    const float* Ws[4] = {w1, w2, w3, pw1};
    const float* Bs[4] = {b1, b2, b3, nullptr};

    float (*sA)[C_ + 1] = XA;
    float (*sB)[C_ + 1] = XB;

    for (int layer = 0; layer < 4; ++layer) {
        __syncthreads();
        for (int e = t; e < C_ * C_ / 4; e += 256)
            reinterpret_cast<float4*>(W)[e] =
                reinterpret_cast<const float4*>(Ws[layer])[e];
        if (t < C_) Bv[t] = (layer == 3) ? 0.0f : Bs[layer][t];
        __syncthreads();
        const bool relu = (layer < 2);
        #pragma unroll
        for (int q = 0; q < 8; ++q) {
            const int row = rg * 8 + q;
            float acc = Bv[c];
            #pragma unroll 8
            for (int k = 0; k < C_; ++k)
                acc = fmaf(sA[row][k], W[k * C_ + c], acc);
            sB[row][c] = relu ? fmaxf(acc, 0.0f) : acc;
        }
        float (*tmp)[C_ + 1] = sA; sA = sB; sB = tmp;
    }
    #pragma unroll
    for (int q = 0; q < 8; ++q) {
        const int row = rg * 8 + q;
        U[(size_t)(rbase + row) * C_ + c] = sA[row][c];
    }
}

// ---------------------------------------------------------------------------
// Kernel 2: split post_w2 into f16 hi (11-bit RN) + f16 lo*2048, TRANSPOSED:
// w2hiT[c][k], w2loT[c][k]
// ---------------------------------------------------------------------------
__global__ __launch_bounds__(256) void prep_w2_kernel(
    const float* __restrict__ pw2,
    _Float16* __restrict__ w2hiT, _Float16* __restrict__ w2loT)
{
    int e = blockIdx.x * 256 + threadIdx.x;   // 4096 elements
    int k = e >> 6, c = e & 63;
    float w = pw2[e];
    unsigned u = __float_as_uint(w);
    float hi = __uint_as_float((u + 0x1000u) & 0xFFFFE000u);  // RN to 11 sig bits
    float lo = (w - hi) * 2048.0f;                             // exact
    w2hiT[c * 64 + k] = (_Float16)hi;   // exact (11 bits fit f16)
    w2loT[c * 64 + k] = (_Float16)lo;   // RN
}

// ---------------------------------------------------------------------------
// Kernel 3: pairwise post-MLP via split-f16 MFMA.
// Transposed GEMM: D[ch][pair] = W2^T (A) x H1^T (B).
// Block: 32 i x 32 j, 4 waves (wave = 16i x 16j quadrant).
// Per wave: 16 pair-tiles (16 i's, one j); per tile 24 MFMA (4 mt x 2 ks x 3).
// ---------------------------------------------------------------------------
__global__ __launch_bounds__(256) void pair_kernel(
    const float* __restrict__ U,
    const _Float16* __restrict__ w2hiT, const _Float16* __restrict__ w2loT,
    const float* __restrict__ pb1, const float* __restrict__ pb2,
    const float* __restrict__ pw3, const float* __restrict__ pb3,
    float* __restrict__ out)
{
    __shared__ float SU[32][68];        // +4 pad: bank spread, keeps 16B align
    __shared__ float SVB[32][68];
    __shared__ float OUTT[32][33][2];

    const int t = threadIdx.x;
    const int lane = t & 63;
    const int wave = t >> 6;
    const int wi = wave >> 1, wj = wave & 1;
    const int zz = blockIdx.z;
    const int ibase = blockIdx.y * 32;
    const int jbase = blockIdx.x * 32;

    {   // stage SU (U rows) and SVB (V rows + post_b1): 8 f32 per thread each
        int r = t >> 3, k0 = (t & 7) * 8;
        const float* up = U + (size_t)(ibase + r) * C_ + k0;
        *reinterpret_cast<float4*>(&SU[r][k0])     = *reinterpret_cast<const float4*>(up);
        *reinterpret_cast<float4*>(&SU[r][k0 + 4]) = *reinterpret_cast<const float4*>(up + 4);
        const float* vp = U + (size_t)((zz ? N_ : 0) + jbase + r) * C_ + k0;
        float4 b0 = *reinterpret_cast<const float4*>(vp);
        float4 b1v = *reinterpret_cast<const float4*>(vp + 4);
        float4 c0 = *reinterpret_cast<const float4*>(pb1 + k0);
        float4 c1 = *reinterpret_cast<const float4*>(pb1 + k0 + 4);
        b0.x += c0.x; b0.y += c0.y; b0.z += c0.z; b0.w += c0.w;
        b1v.x += c1.x; b1v.y += c1.y; b1v.z += c1.z; b1v.w += c1.w;
        *reinterpret_cast<float4*>(&SVB[r][k0])     = b0;
        *reinterpret_cast<float4*>(&SVB[r][k0 + 4]) = b1v;
    }

    const int ch_l = lane & 15;   // A row (channel) within tile / B col (pair)
    const int kg = lane >> 4;     // k-group

    // A-frags: W2^T, lane holds A[row=mt*16+ch_l][k = ks*32 + kg*8 + e]
    f16x8 whi[4][2], wlo[4][2];
    #pragma unroll
    for (int mt = 0; mt < 4; ++mt)
        #pragma unroll
        for (int ks = 0; ks < 2; ++ks) {
            int off = (mt * 16 + ch_l) * 64 + ks * 32 + kg * 8;
            whi[mt][ks] = *reinterpret_cast<const f16x8*>(w2hiT + off);
            wlo[mt][ks] = *reinterpret_cast<const f16x8*>(w2loT + off);
        }

    // per-lane b2 / w3 for D rows ch = mt*16 + kg*4 + r
    float b2v[16], w30[16], w31[16];
    #pragma unroll
    for (int mt = 0; mt < 4; ++mt)
        #pragma unroll
        for (int r = 0; r < 4; ++r) {
            int ch = mt * 16 + kg * 4 + r;
            b2v[mt * 4 + r] = pb2[ch];
            w30[mt * 4 + r] = pw3[ch * 2];
            w31[mt * 4 + r] = pw3[ch * 2 + 1];
        }
    const float ob0 = pb3[0], ob1 = pb3[1];

    __syncthreads();

    // hoist su: this lane's pair row is i = wi*16 + ch_l, k's = ks*32+kg*8+e
    float su[2][8];
    #pragma unroll
    for (int ks = 0; ks < 2; ++ks) {
        int k0 = ks * 32 + kg * 8;
        float4 a = *reinterpret_cast<const float4*>(&SU[wi * 16 + ch_l][k0]);
        float4 b = *reinterpret_cast<const float4*>(&SU[wi * 16 + ch_l][k0 + 4]);
        su[ks][0] = a.x; su[ks][1] = a.y; su[ks][2] = a.z; su[ks][3] = a.w;
        su[ks][4] = b.x; su[ks][5] = b.y; su[ks][6] = b.z; su[ks][7] = b.w;
    }

    for (int jj = 0; jj < 16; ++jj) {
        const int jr = wj * 16 + jj;
        f16x8 bhi[2], blo[2];
        #pragma unroll
        for (int ks = 0; ks < 2; ++ks) {
            int k0 = ks * 32 + kg * 8;
            float4 a = *reinterpret_cast<const float4*>(&SVB[jr][k0]);      // broadcast
            float4 b = *reinterpret_cast<const float4*>(&SVB[jr][k0 + 4]);
            float sv[8] = {a.x, a.y, a.z, a.w, b.x, b.y, b.z, b.w};
            #pragma unroll
            for (int e = 0; e < 8; ++e) {
                float x = fmaxf(su[ks][e] + sv[e], 0.0f);      // h1
                unsigned u = __float_as_uint(x);
                float hi = __uint_as_float((u + 0x1000u) & 0xFFFFE000u);
                float lo = (x - hi) * 2048.0f;
                bhi[ks][e] = (_Float16)hi;
                blo[ks][e] = (_Float16)lo;
            }
        }
        f32x4 ah[4], al[4];
        #pragma unroll
        for (int mt = 0; mt < 4; ++mt) {
            ah[mt] = f32x4{b2v[4 * mt], b2v[4 * mt + 1], b2v[4 * mt + 2], b2v[4 * mt + 3]};
            al[mt] = f32x4{0.0f, 0.0f, 0.0f, 0.0f};
        }
        #pragma unroll
        for (int ks = 0; ks < 2; ++ks)
            #pragma unroll
            for (int mt = 0; mt < 4; ++mt) {
                ah[mt] = __builtin_amdgcn_mfma_f32_16x16x32_f16(whi[mt][ks], bhi[ks], ah[mt], 0, 0, 0);
                al[mt] = __builtin_amdgcn_mfma_f32_16x16x32_f16(whi[mt][ks], blo[ks], al[mt], 0, 0, 0);
                al[mt] = __builtin_amdgcn_mfma_f32_16x16x32_f16(wlo[mt][ks], bhi[ks], al[mt], 0, 0, 0);
            }
        // epilogue: h2 = relu(ah + al/2048) (b2 folded in ah init); layer3 dot
        float p0 = 0.0f, p1 = 0.0f;
        #pragma unroll
        for (int mt = 0; mt < 4; ++mt)
            #pragma unroll
            for (int r = 0; r < 4; ++r) {
                float g = fmaxf(ah[mt][r] + al[mt][r] * (1.0f / 2048.0f), 0.0f);
                p0 = fmaf(g, w30[4 * mt + r], p0);
                p1 = fmaf(g, w31[4 * mt + r], p1);
            }
        // reduce over the 4 kg groups (each lane holds 16 of 64 channels)
        p0 += __shfl_xor(p0, 16); p0 += __shfl_xor(p0, 32);
        p1 += __shfl_xor(p1, 16); p1 += __shfl_xor(p1, 32);
        if (lane < 16) {
            OUTT[wi * 16 + lane][wj * 16 + jj][0] = p0 + ob0;
            OUTT[wi * 16 + lane][wj * 16 + jj][1] = p1 + ob1;
        }
    }
    __syncthreads();
    {   // coalesced-ish write out
        float* obase = out + (size_t)zz * (2ull * N_ * M_);
        int r = t >> 3;
        int q0 = (t & 7) * 4;
        int i = ibase + r;
        #pragma unroll
        for (int q = 0; q < 4; ++q) {
            int j = jbase + q0 + q;
            float2 v = *reinterpret_cast<float2*>(&OUTT[r][q0 + q][0]);
            *reinterpret_cast<float2*>(obase + ((size_t)i * M_ + j) * 2) = v;
        }
    }
}

// ---------------------------------------------------------------------------
// Kernel 4: colmax stage 1 — top-2 per (32-row chunk, column) of sigmoid(st[...,0])
// grid (4 j-tiles, 32 i-chunks) x 256
// ---------------------------------------------------------------------------
__global__ __launch_bounds__(256) void colmax1_kernel(
    const float* __restrict__ Lst, unsigned long long* __restrict__ PT2)
{
    int j = blockIdx.x * 256 + threadIdx.x;
    int ic = blockIdx.y;
    unsigned long long k1 = 0, k2 = 0;
    for (int q = 0; q < 32; ++q) {
        int i = ic * 32 + q;
        float v = sig(Lst[((size_t)i * M_ + j) * 2]);
        unsigned long long k = packkey(v, (unsigned)i);
        if (k > k1) { k2 = k1; k1 = k; } else if (k > k2) k2 = k;
    }
    PT2[((size_t)ic * M_ + j) * 2]     = k1;
    PT2[((size_t)ic * M_ + j) * 2 + 1] = k2;
}

// ---------------------------------------------------------------------------
// Kernel 5: colmax stage 2 — merge to global top-2; flag near-ties; init rowbest.
// colinfo[j] = {top1_i, (gap<1e-4) ? top2_i : -1}
// ---------------------------------------------------------------------------
__global__ __launch_bounds__(256) void colmax2_kernel(
    const unsigned long long* __restrict__ PT2,
    int2* __restrict__ colinfo, unsigned long long* __restrict__ rowbest)
{
    int j = blockIdx.x * 256 + threadIdx.x;
    unsigned long long k1 = 0, k2 = 0;
    for (int ic = 0; ic < 32; ++ic) {
        unsigned long long a = PT2[((size_t)ic * M_ + j) * 2];
        unsigned long long b = PT2[((size_t)ic * M_ + j) * 2 + 1];
        if (a > k1) { k2 = k1; k1 = a; } else if (a > k2) k2 = a;
        if (b > k1) { k2 = k1; k1 = b; } else if (b > k2) k2 = b;
    }
    int i1 = (int)(0xFFFFFFFFu - (unsigned)(k1 & 0xFFFFFFFFull));
    int i2 = (int)(0xFFFFFFFFu - (unsigned)(k2 & 0xFFFFFFFFull));
    float v1 = __uint_as_float((unsigned)(k1 >> 32));
    float v2 = __uint_as_float((unsigned)(k2 >> 32));
    int2 info; info.x = i1; info.y = (v1 - v2 < 1e-4f) ? i2 : -1;
    colinfo[j] = info;
    rowbest[j] = 0ull;
}

// ---------------------------------------------------------------------------
// Kernel 6: exact f32 recompute of match value for each column's winner
// (and argmax between top-2 candidates when flagged). 1 wave per column.
// Rewrites colinfo[j] = {winner_i, float_bits(exact sigmoid)}
// ---------------------------------------------------------------------------
__global__ __launch_bounds__(64) void exactvals_kernel(
    const float* __restrict__ U, const float* __restrict__ pb1,
    const float* __restrict__ pw2, const float* __restrict__ pb2,
    const float* __restrict__ pw3, const float* __restrict__ pb3,
    int2* __restrict__ colinfo)
{
    __shared__ float h1s[64];
    int j = blockIdx.x;
    int lane = threadIdx.x;
    int2 info = colinfo[j];
    int ids[2] = {info.x, info.y};
    int nc = (info.y >= 0) ? 2 : 1;
    float vals[2] = {0.0f, 0.0f};
    for (int cnd = 0; cnd < nc; ++cnd) {
        int i = ids[cnd];
        h1s[lane] = fmaxf(U[(size_t)i * C_ + lane] + U[(size_t)(N_ + j) * C_ + lane] + pb1[lane], 0.0f);
        __syncthreads();
        float acc = pb2[lane];
        for (int k = 0; k < 64; ++k)
            acc = fmaf(h1s[k], pw2[k * 64 + lane], acc);
        float g = fmaxf(acc, 0.0f);
        float p = g * pw3[lane * 2];
        #pragma unroll
        for (int m = 1; m < 64; m <<= 1) p += __shfl_xor(p, m);
        vals[cnd] = sig(p + pb3[0]);
        __syncthreads();
    }
    int wi; float wv;
    if (nc == 1) { wi = ids[0]; wv = vals[0]; }
    else if (vals[0] > vals[1]) { wi = ids[0]; wv = vals[0]; }
    else if (vals[1] > vals[0]) { wi = ids[1]; wv = vals[1]; }
    else { wi = min(ids[0], ids[1]); wv = vals[0]; }
    if (lane == 0) { int2 r; r.x = wi; r.y = (int)__float_as_uint(wv); colinfo[j] = r; }
}

// ---------------------------------------------------------------------------
// Kernel 7: row argmax via candidate inversion: only (col_arg[j], j) pairs matter.
// ---------------------------------------------------------------------------
__global__ __launch_bounds__(256) void rowatomic_kernel(
    const int2* __restrict__ colinfo, unsigned long long* __restrict__ rowbest)
{
    int j = blockIdx.x * 256 + threadIdx.x;
    int2 info = colinfo[j];
    unsigned long long key =
        ((unsigned long long)(unsigned)info.y << 32) | (unsigned)(0xFFFFFFFFu - (unsigned)j);
    atomicMax(&rowbest[info.x], key);
}

// ---------------------------------------------------------------------------
// Kernel 8/9: zero matched, then scatter the <=1024 mutual matches.
// ---------------------------------------------------------------------------
__global__ __launch_bounds__(256) void zerofill_kernel(float* __restrict__ matched)
{
    int idx = (blockIdx.x * 256 + threadIdx.x) * 4;
    *reinterpret_cast<float4*>(matched + idx) = float4{0.0f, 0.0f, 0.0f, 0.0f};
}

__global__ __launch_bounds__(256) void scatter_kernel(
    const unsigned long long* __restrict__ rowbest, float* __restrict__ matched)
{
    int i = blockIdx.x * 256 + threadIdx.x;
    unsigned long long key = rowbest[i];
    if (key) {
        unsigned j = 0xFFFFFFFFu - (unsigned)(key & 0xFFFFFFFFull);
        matched[(size_t)i * M_ + j] = __uint_as_float((unsigned)(key >> 32));
    }
}

} // namespace

extern "C" void kernel_launch(void* const* d_in, const int* in_sizes, int n_in,
                              void* d_out, int out_size, void* d_ws, size_t ws_size,
                              hipStream_t stream)
{
    const float* step_x  = (const float*)d_in[0];
    const float* state_x = (const float*)d_in[1];
    const float* pre_w1  = (const float*)d_in[2];
    const float* pre_b1  = (const float*)d_in[3];
    const float* pre_w2  = (const float*)d_in[4];
    const float* pre_b2  = (const float*)d_in[5];
    const float* pre_w3  = (const float*)d_in[6];
    const float* pre_b3  = (const float*)d_in[7];
    const float* post_w1 = (const float*)d_in[8];
    const float* post_b1 = (const float*)d_in[9];
    const float* post_w2 = (const float*)d_in[10];
    const float* post_b2 = (const float*)d_in[11];
    const float* post_w3 = (const float*)d_in[12];
    const float* post_b3 = (const float*)d_in[13];

    float* out     = (float*)d_out;
    float* Lst     = out + 2ull * N_ * M_;
    float* matched = out + 4ull * N_ * M_;

    // ws: U (512KB) + rowbest (8KB)  -- round 2 proved ws >= 528KB
    float* U = (float*)d_ws;
    unsigned long long* rowbest = (unsigned long long*)((char*)d_ws + 2048ull * 64 * 4);

    // scratch inside 'matched' (4MB), consumed before zerofill:
    char* ms = (char*)matched;
    unsigned long long* PT2 = (unsigned long long*)ms;            // 512KB (colmax1->colmax2)
    int2*      colinfo = (int2*)(ms + 512 * 1024);                // 8KB
    _Float16*  w2hiT   = (_Float16*)(ms + 520 * 1024);            // 8KB (prep->pair)
    _Float16*  w2loT   = (_Float16*)(ms + 528 * 1024);            // 8KB

    hipLaunchKernelGGL(pre_kernel, dim3(64), dim3(256), 0, stream,
        step_x, state_x, pre_w1, pre_b1, pre_w2, pre_b2, pre_w3, pre_b3,
        post_w1, U);
    hipLaunchKernelGGL(prep_w2_kernel, dim3(16), dim3(256), 0, stream,
        post_w2, w2hiT, w2loT);
    hipLaunchKernelGGL(pair_kernel, dim3(32, 32, 2), dim3(256), 0, stream,
        U, w2hiT, w2loT, post_b1, post_b2, post_w3, post_b3, out);
    hipLaunchKernelGGL(colmax1_kernel, dim3(4, 32), dim3(256), 0, stream,
        Lst, PT2);
    hipLaunchKernelGGL(colmax2_kernel, dim3(4), dim3(256), 0, stream,
        PT2, colinfo, rowbest);
    hipLaunchKernelGGL(exactvals_kernel, dim3(1024), dim3(64), 0, stream,
        U, post_b1, post_w2, post_b2, post_w3, post_b3, colinfo);
    hipLaunchKernelGGL(rowatomic_kernel, dim3(4), dim3(256), 0, stream,
        colinfo, rowbest);
    hipLaunchKernelGGL(zerofill_kernel, dim3(1024), dim3(256), 0, stream,
        matched);
    hipLaunchKernelGGL(scatter_kernel, dim3(4), dim3(256), 0, stream,
        rowbest, matched);
}

// Round 4
// 158.169 us; speedup vs baseline: 2.4097x; 1.3517x over previous
//
#include <hip/hip_runtime.h>
#include <math.h>

namespace {

constexpr int N_ = 1024;
constexpr int M_ = 1024;
constexpr int C_ = 64;

typedef _Float16 f16x8 __attribute__((ext_vector_type(8)));
typedef float f32x4 __attribute__((ext_vector_type(4)));
static_assert(sizeof(f16x8) == 16, "f16x8 must be 4 VGPRs");

__device__ __forceinline__ float sig(float x) { return 1.0f / (1.0f + expf(-x)); }

// order-preserving float->uint for ANY float (incl. negatives)
__device__ __forceinline__ unsigned flipbits(float f) {
    unsigned u = __float_as_uint(f);
    return u ^ (0x80000000u | (unsigned)((int)u >> 31));
}
__device__ __forceinline__ float unflipbits(unsigned k) {
    unsigned u = (k & 0x80000000u) ? (k ^ 0x80000000u) : ~k;
    return __uint_as_float(u);
}
// logit-domain key: bigger logit wins, tie -> smaller index
__device__ __forceinline__ unsigned long long packlogit(float v, unsigned idx) {
    return ((unsigned long long)flipbits(v) << 32) | (unsigned)(0xFFFFFFFFu - idx);
}
// positive-sigmoid key (exact values from exactvals)
__device__ __forceinline__ unsigned long long packpos(float v, unsigned idx) {
    return ((unsigned long long)__float_as_uint(v) << 32) | (unsigned)(0xFFFFFFFFu - idx);
}

// ---------------------------------------------------------------------------
// Kernel 1: blocks 0..127: pre-MLP (3 layers) + projection through post_w1,
// 16 rows per block. Block 128: transpose post_w2 to f16 w2T[c][k].
// rows 0..1023 = step_x, rows 1024..2047 = state_x.
// ---------------------------------------------------------------------------
__global__ __launch_bounds__(256) void pre_prep_kernel(
    const float* __restrict__ step_x, const float* __restrict__ state_x,
    const float* __restrict__ w1, const float* __restrict__ b1,
    const float* __restrict__ w2, const float* __restrict__ b2,
    const float* __restrict__ w3, const float* __restrict__ b3,
    const float* __restrict__ pw1, const float* __restrict__ pw2,
    float* __restrict__ U, _Float16* __restrict__ w2T)
{
    const int t = threadIdx.x;
    if (blockIdx.x == 128) {             // w2 prep: transposed f16
        for (int e = t; e < C_ * C_; e += 256) {
            int k = e >> 6, c = e & 63;
            w2T[c * 64 + k] = (_Float16)pw2[e];
        }
        return;
    }

    __shared__ float XA[16][C_ + 1];
    __shared__ float XB[16][C_ + 1];
    __shared__ float W[C_ * C_];
    __shared__ float Bv[C_];

    const int c = t & 63;
    const int rg = t >> 6;               // 0..3, 4 rows each
    const int rbase = blockIdx.x * 16;

    const float* src_g = (rbase < N_) ? (step_x + (size_t)rbase * C_)
                                      : (state_x + (size_t)(rbase - N_) * C_);
    {   // 16 rows x 64 = 256 float4, one per thread
        int row = t >> 4, k4 = (t & 15) << 2;
        float4 v = *reinterpret_cast<const float4*>(src_g + row * C_ + k4);
        XA[row][k4 + 0] = v.x; XA[row][k4 + 1] = v.y;
        XA[row][k4 + 2] = v.z; XA[row][k4 + 3] = v.w;
    }

    const float* Ws[4] = {w1, w2, w3, pw1};
    const float* Bs[4] = {b1, b2, b3, nullptr};

    float (*sA)[C_ + 1] = XA;
    float (*sB)[C_ + 1] = XB;

    for (int layer = 0; layer < 4; ++layer) {
        __syncthreads();
        for (int e = t; e < C_ * C_ / 4; e += 256)
            reinterpret_cast<float4*>(W)[e] =
                reinterpret_cast<const float4*>(Ws[layer])[e];
        if (t < C_) Bv[t] = (layer == 3) ? 0.0f : Bs[layer][t];
        __syncthreads();
        const bool relu = (layer < 2);
        #pragma unroll
        for (int q = 0; q < 4; ++q) {
            const int row = rg * 4 + q;
            float acc = Bv[c];
            #pragma unroll 8
            for (int k = 0; k < C_; ++k)
                acc = fmaf(sA[row][k], W[k * C_ + c], acc);
            sB[row][c] = relu ? fmaxf(acc, 0.0f) : acc;
        }
        float (*tmp)[C_ + 1] = sA; sA = sB; sB = tmp;
    }
    #pragma unroll
    for (int q = 0; q < 4; ++q) {
        const int row = rg * 4 + q;
        U[(size_t)(rbase + row) * C_ + c] = sA[row][c];
    }
}

// ---------------------------------------------------------------------------
// Kernel 2: pairwise post-MLP via single-f16 MFMA.
// Transposed GEMM: D[ch][pair] = W2^T (A) x H1^T (B).
// Block: 32 i x 32 j, 4 waves (wave = 16i x 16j quadrant).
// ---------------------------------------------------------------------------
__global__ __launch_bounds__(256) void pair_kernel(
    const float* __restrict__ U,
    const _Float16* __restrict__ w2T,
    const float* __restrict__ pb1, const float* __restrict__ pb2,
    const float* __restrict__ pw3, const float* __restrict__ pb3,
    float* __restrict__ out)
{
    __shared__ float SU[32][68];
    __shared__ float SVB[32][68];
    __shared__ float OUTT[32][33][2];

    const int t = threadIdx.x;
    const int lane = t & 63;
    const int wave = t >> 6;
    const int wi = wave >> 1, wj = wave & 1;
    const int zz = blockIdx.z;
    const int ibase = blockIdx.y * 32;
    const int jbase = blockIdx.x * 32;

    {   // stage SU (U rows) and SVB (V rows + post_b1): 8 f32 per thread each
        int r = t >> 3, k0 = (t & 7) * 8;
        const float* up = U + (size_t)(ibase + r) * C_ + k0;
        *reinterpret_cast<float4*>(&SU[r][k0])     = *reinterpret_cast<const float4*>(up);
        *reinterpret_cast<float4*>(&SU[r][k0 + 4]) = *reinterpret_cast<const float4*>(up + 4);
        const float* vp = U + (size_t)((zz ? N_ : 0) + jbase + r) * C_ + k0;
        float4 b0 = *reinterpret_cast<const float4*>(vp);
        float4 b1v = *reinterpret_cast<const float4*>(vp + 4);
        float4 c0 = *reinterpret_cast<const float4*>(pb1 + k0);
        float4 c1 = *reinterpret_cast<const float4*>(pb1 + k0 + 4);
        b0.x += c0.x; b0.y += c0.y; b0.z += c0.z; b0.w += c0.w;
        b1v.x += c1.x; b1v.y += c1.y; b1v.z += c1.z; b1v.w += c1.w;
        *reinterpret_cast<float4*>(&SVB[r][k0])     = b0;
        *reinterpret_cast<float4*>(&SVB[r][k0 + 4]) = b1v;
    }

    const int ch_l = lane & 15;   // A row (channel) within tile / B col (pair)
    const int kg = lane >> 4;     // k-group

    // A-frags: W2^T, lane holds A[row=mt*16+ch_l][k = ks*32 + kg*8 + e]
    f16x8 whi[4][2];
    #pragma unroll
    for (int mt = 0; mt < 4; ++mt)
        #pragma unroll
        for (int ks = 0; ks < 2; ++ks)
            whi[mt][ks] = *reinterpret_cast<const f16x8*>(
                w2T + (mt * 16 + ch_l) * 64 + ks * 32 + kg * 8);

    // per-lane b2 / w3 for D rows ch = mt*16 + kg*4 + r
    float b2v[16], w30[16], w31[16];
    #pragma unroll
    for (int mt = 0; mt < 4; ++mt)
        #pragma unroll
        for (int r = 0; r < 4; ++r) {
            int ch = mt * 16 + kg * 4 + r;
            b2v[mt * 4 + r] = pb2[ch];
            w30[mt * 4 + r] = pw3[ch * 2];
            w31[mt * 4 + r] = pw3[ch * 2 + 1];
        }
    const float ob0 = pb3[0], ob1 = pb3[1];

    __syncthreads();

    // hoist su: this lane's pair row is i = wi*16 + ch_l
    float su[2][8];
    #pragma unroll
    for (int ks = 0; ks < 2; ++ks) {
        int k0 = ks * 32 + kg * 8;
        float4 a = *reinterpret_cast<const float4*>(&SU[wi * 16 + ch_l][k0]);
        float4 b = *reinterpret_cast<const float4*>(&SU[wi * 16 + ch_l][k0 + 4]);
        su[ks][0] = a.x; su[ks][1] = a.y; su[ks][2] = a.z; su[ks][3] = a.w;
        su[ks][4] = b.x; su[ks][5] = b.y; su[ks][6] = b.z; su[ks][7] = b.w;
    }

    for (int jj = 0; jj < 16; ++jj) {
        const int jr = wj * 16 + jj;
        f16x8 bhi[2];
        #pragma unroll
        for (int ks = 0; ks < 2; ++ks) {
            int k0 = ks * 32 + kg * 8;
            float4 a = *reinterpret_cast<const float4*>(&SVB[jr][k0]);      // broadcast
            float4 b = *reinterpret_cast<const float4*>(&SVB[jr][k0 + 4]);
            float sv[8] = {a.x, a.y, a.z, a.w, b.x, b.y, b.z, b.w};
            #pragma unroll
            for (int e = 0; e < 8; ++e)
                bhi[ks][e] = (_Float16)fmaxf(su[ks][e] + sv[e], 0.0f);  // h1
        }
        f32x4 ah[4];
        #pragma unroll
        for (int mt = 0; mt < 4; ++mt)
            ah[mt] = f32x4{b2v[4 * mt], b2v[4 * mt + 1], b2v[4 * mt + 2], b2v[4 * mt + 3]};
        #pragma unroll
        for (int ks = 0; ks < 2; ++ks)
            #pragma unroll
            for (int mt = 0; mt < 4; ++mt)
                ah[mt] = __builtin_amdgcn_mfma_f32_16x16x32_f16(whi[mt][ks], bhi[ks], ah[mt], 0, 0, 0);
        // epilogue: h2 = relu(acc) (b2 folded into init); layer3 dot
        float p0 = 0.0f, p1 = 0.0f;
        #pragma unroll
        for (int mt = 0; mt < 4; ++mt)
            #pragma unroll
            for (int r = 0; r < 4; ++r) {
                float g = fmaxf(ah[mt][r], 0.0f);
                p0 = fmaf(g, w30[4 * mt + r], p0);
                p1 = fmaf(g, w31[4 * mt + r], p1);
            }
        // reduce over the 4 kg groups (each lane holds 16 of 64 channels)
        p0 += __shfl_xor(p0, 16); p0 += __shfl_xor(p0, 32);
        p1 += __shfl_xor(p1, 16); p1 += __shfl_xor(p1, 32);
        if (lane < 16) {
            OUTT[wi * 16 + lane][wj * 16 + jj][0] = p0 + ob0;
            OUTT[wi * 16 + lane][wj * 16 + jj][1] = p1 + ob1;
        }
    }
    __syncthreads();
    {   // write out
        float* obase = out + (size_t)zz * (2ull * N_ * M_);
        int r = t >> 3;
        int q0 = (t & 7) * 4;
        int i = ibase + r;
        #pragma unroll
        for (int q = 0; q < 4; ++q) {
            int j = jbase + q0 + q;
            float2 v = *reinterpret_cast<float2*>(&OUTT[r][q0 + q][0]);
            *reinterpret_cast<float2*>(obase + ((size_t)i * M_ + j) * 2) = v;
        }
    }
}

// ---------------------------------------------------------------------------
// Kernel 3: colmax stage 1 — top-2 (by raw logit, bit-flipped keys) per
// (32-row chunk, column). grid (4 j-tiles, 32 i-chunks) x 256. No sigmoid:
// argmax over sigmoid == argmax over logit (monotone).
// ---------------------------------------------------------------------------
__global__ __launch_bounds__(256) void colmax1_kernel(
    const float* __restrict__ Lst, unsigned long long* __restrict__ PT2)
{
    int j = blockIdx.x * 256 + threadIdx.x;
    int ic = blockIdx.y;
    unsigned long long k1 = 0, k2 = 0;
    for (int q = 0; q < 32; ++q) {
        int i = ic * 32 + q;
        unsigned long long k = packlogit(Lst[((size_t)i * M_ + j) * 2], (unsigned)i);
        if (k > k1) { k2 = k1; k1 = k; } else if (k > k2) k2 = k;
    }
    PT2[((size_t)ic * M_ + j) * 2]     = k1;
    PT2[((size_t)ic * M_ + j) * 2 + 1] = k2;
}

// ---------------------------------------------------------------------------
// Kernel 4: colmax stage 2 — merge to global top-2; flag near-ties (logit gap
// < 8e-3, ~8x the f16 error); init rowbest. grid 8 x 128.
// ---------------------------------------------------------------------------
__global__ __launch_bounds__(128) void colmax2_kernel(
    const unsigned long long* __restrict__ PT2,
    int2* __restrict__ colinfo, unsigned long long* __restrict__ rowbest)
{
    int j = blockIdx.x * 128 + threadIdx.x;
    unsigned long long k1 = 0, k2 = 0;
    for (int ic = 0; ic < 32; ++ic) {
        unsigned long long a = PT2[((size_t)ic * M_ + j) * 2];
        unsigned long long b = PT2[((size_t)ic * M_ + j) * 2 + 1];
        if (a > k1) { k2 = k1; k1 = a; } else if (a > k2) k2 = a;
        if (b > k1) { k2 = k1; k1 = b; } else if (b > k2) k2 = b;
    }
    int i1 = (int)(0xFFFFFFFFu - (unsigned)(k1 & 0xFFFFFFFFull));
    int i2 = (int)(0xFFFFFFFFu - (unsigned)(k2 & 0xFFFFFFFFull));
    float v1 = unflipbits((unsigned)(k1 >> 32));
    float v2 = unflipbits((unsigned)(k2 >> 32));
    int2 info; info.x = i1; info.y = (v1 - v2 < 8e-3f) ? i2 : -1;
    colinfo[j] = info;
    rowbest[j] = 0ull;
}

// ---------------------------------------------------------------------------
// Kernel 5: exact f32 recompute of the column winner's logit (both candidates
// when flagged); winner value = exact sigmoid; lane0 does the row-argmax
// atomic directly. 1 wave per column.
// ---------------------------------------------------------------------------
__global__ __launch_bounds__(64) void exactvals_kernel(
    const float* __restrict__ U, const float* __restrict__ pb1,
    const float* __restrict__ pw2, const float* __restrict__ pb2,
    const float* __restrict__ pw3, const float* __restrict__ pb3,
    const int2* __restrict__ colinfo, unsigned long long* __restrict__ rowbest)
{
    __shared__ float h1s[64];
    int j = blockIdx.x;
    int lane = threadIdx.x;
    int2 info = colinfo[j];
    int ids[2] = {info.x, info.y};
    int nc = (info.y >= 0) ? 2 : 1;
    float logits[2] = {0.0f, 0.0f};
    for (int cnd = 0; cnd < nc; ++cnd) {
        int i = ids[cnd];
        h1s[lane] = fmaxf(U[(size_t)i * C_ + lane] + U[(size_t)(N_ + j) * C_ + lane] + pb1[lane], 0.0f);
        __syncthreads();
        float acc = pb2[lane];
        #pragma unroll 8
        for (int k = 0; k < 64; ++k)
            acc = fmaf(h1s[k], pw2[k * 64 + lane], acc);
        float p = fmaxf(acc, 0.0f) * pw3[lane * 2];
        #pragma unroll
        for (int m = 1; m < 64; m <<= 1) p += __shfl_xor(p, m);
        logits[cnd] = p + pb3[0];
        __syncthreads();
    }
    int wi; float wp;
    if (nc == 1) { wi = ids[0]; wp = logits[0]; }
    else if (logits[0] > logits[1]) { wi = ids[0]; wp = logits[0]; }
    else if (logits[1] > logits[0]) { wi = ids[1]; wp = logits[1]; }
    else { wi = min(ids[0], ids[1]); wp = logits[0]; }
    if (lane == 0)
        atomicMax(&rowbest[wi], packpos(sig(wp), (unsigned)j));
}

// ---------------------------------------------------------------------------
// Kernel 6: zero matched row + scatter that row's mutual match (if any).
// grid 1024 (one block per row i).
// ---------------------------------------------------------------------------
__global__ __launch_bounds__(256) void zscatter_kernel(
    const unsigned long long* __restrict__ rowbest, float* __restrict__ matched)
{
    int i = blockIdx.x;
    int t = threadIdx.x;
    *reinterpret_cast<float4*>(matched + (size_t)i * M_ + t * 4) =
        float4{0.0f, 0.0f, 0.0f, 0.0f};
    __syncthreads();
    if (t == 0) {
        unsigned long long key = rowbest[i];
        if (key) {
            unsigned j = 0xFFFFFFFFu - (unsigned)(key & 0xFFFFFFFFull);
            matched[(size_t)i * M_ + j] = __uint_as_float((unsigned)(key >> 32));
        }
    }
}

} // namespace

extern "C" void kernel_launch(void* const* d_in, const int* in_sizes, int n_in,
                              void* d_out, int out_size, void* d_ws, size_t ws_size,
                              hipStream_t stream)
{
    const float* step_x  = (const float*)d_in[0];
    const float* state_x = (const float*)d_in[1];
    const float* pre_w1  = (const float*)d_in[2];
    const float* pre_b1  = (const float*)d_in[3];
    const float* pre_w2  = (const float*)d_in[4];
    const float* pre_b2  = (const float*)d_in[5];
    const float* pre_w3  = (const float*)d_in[6];
    const float* pre_b3  = (const float*)d_in[7];
    const float* post_w1 = (const float*)d_in[8];
    const float* post_b1 = (const float*)d_in[9];
    const float* post_w2 = (const float*)d_in[10];
    const float* post_b2 = (const float*)d_in[11];
    const float* post_w3 = (const float*)d_in[12];
    const float* post_b3 = (const float*)d_in[13];

    float* out     = (float*)d_out;
    float* Lst     = out + 2ull * N_ * M_;
    float* matched = out + 4ull * N_ * M_;

    // ws: U (512KB) + rowbest (8KB)
    float* U = (float*)d_ws;
    unsigned long long* rowbest = (unsigned long long*)((char*)d_ws + 2048ull * 64 * 4);

    // scratch inside 'matched' (4MB), all consumed before zscatter rewrites it:
    char* ms = (char*)matched;
    unsigned long long* PT2 = (unsigned long long*)ms;            // 512KB (colmax1->colmax2)
    int2*      colinfo = (int2*)(ms + 512 * 1024);                // 8KB
    _Float16*  w2T     = (_Float16*)(ms + 520 * 1024);            // 8KB (pre->pair)

    hipLaunchKernelGGL(pre_prep_kernel, dim3(129), dim3(256), 0, stream,
        step_x, state_x, pre_w1, pre_b1, pre_w2, pre_b2, pre_w3, pre_b3,
        post_w1, post_w2, U, w2T);
    hipLaunchKernelGGL(pair_kernel, dim3(32, 32, 2), dim3(256), 0, stream,
        U, w2T, post_b1, post_b2, post_w3, post_b3, out);
    hipLaunchKernelGGL(colmax1_kernel, dim3(4, 32), dim3(256), 0, stream,
        Lst, PT2);
    hipLaunchKernelGGL(colmax2_kernel, dim3(8), dim3(128), 0, stream,
        PT2, colinfo, rowbest);
    hipLaunchKernelGGL(exactvals_kernel, dim3(1024), dim3(64), 0, stream,
        U, post_b1, post_w2, post_b2, post_w3, post_b3, colinfo, rowbest);
    hipLaunchKernelGGL(zscatter_kernel, dim3(1024), dim3(256), 0, stream,
        rowbest, matched);
}

// Round 7
// 147.230 us; speedup vs baseline: 2.5887x; 1.0743x over previous
//
#include <hip/hip_runtime.h>
#include <math.h>

namespace {

constexpr int N_ = 1024;
constexpr int M_ = 1024;
constexpr int C_ = 64;

typedef _Float16 f16x8 __attribute__((ext_vector_type(8)));
typedef __fp16 fp16x2 __attribute__((ext_vector_type(2)));   // cvt_pkrtz native type
typedef float f32x4 __attribute__((ext_vector_type(4)));
static_assert(sizeof(f16x8) == 16, "f16x8 must be 4 VGPRs");

__device__ __forceinline__ float sig(float x) { return 1.0f / (1.0f + expf(-x)); }

// order-preserving float->uint for ANY float (incl. negatives)
__device__ __forceinline__ unsigned flipbits(float f) {
    unsigned u = __float_as_uint(f);
    return u ^ (0x80000000u | (unsigned)((int)u >> 31));
}
__device__ __forceinline__ float unflipbits(unsigned k) {
    unsigned u = (k & 0x80000000u) ? (k ^ 0x80000000u) : ~k;
    return __uint_as_float(u);
}
// logit-domain key: bigger logit wins, tie -> smaller index
__device__ __forceinline__ unsigned long long packlogit(float v, unsigned idx) {
    return ((unsigned long long)flipbits(v) << 32) | (unsigned)(0xFFFFFFFFu - idx);
}
// positive-sigmoid key (exact values)
__device__ __forceinline__ unsigned long long packpos(float v, unsigned idx) {
    return ((unsigned long long)__float_as_uint(v) << 32) | (unsigned)(0xFFFFFFFFu - idx);
}
__device__ __forceinline__ unsigned long long shflx64(unsigned long long v, int m) {
    unsigned lo = __shfl_xor((unsigned)v, m);
    unsigned hi = __shfl_xor((unsigned)(v >> 32), m);
    return ((unsigned long long)hi << 32) | lo;
}

// ---------------------------------------------------------------------------
// Kernel 1: blocks 0..127: pre-MLP (3 layers) + projection through post_w1,
// 16 rows per block. Block 128: w2T prep + rowbest zero.
// rows 0..1023 = step_x, rows 1024..2047 = state_x.
// ---------------------------------------------------------------------------
__global__ __launch_bounds__(256) void pre_prep_kernel(
    const float* __restrict__ step_x, const float* __restrict__ state_x,
    const float* __restrict__ w1, const float* __restrict__ b1,
    const float* __restrict__ w2, const float* __restrict__ b2,
    const float* __restrict__ w3, const float* __restrict__ b3,
    const float* __restrict__ pw1, const float* __restrict__ pw2,
    float* __restrict__ U, _Float16* __restrict__ w2T,
    unsigned long long* __restrict__ rowbest)
{
    const int t = threadIdx.x;
    if (blockIdx.x == 128) {             // w2 prep (transposed f16) + rowbest zero
        for (int e = t; e < C_ * C_; e += 256) {
            int k = e >> 6, c = e & 63;
            w2T[c * 64 + k] = (_Float16)pw2[e];
        }
        for (int e = t; e < 1024; e += 256) rowbest[e] = 0ull;
        return;
    }

    __shared__ float XA[16][C_ + 1];
    __shared__ float XB[16][C_ + 1];
    __shared__ float W[C_ * C_];
    __shared__ float Bv[C_];

    const int c = t & 63;
    const int rg = t >> 6;               // 0..3, 4 rows each
    const int rbase = blockIdx.x * 16;

    const float* src_g = (rbase < N_) ? (step_x + (size_t)rbase * C_)
                                      : (state_x + (size_t)(rbase - N_) * C_);
    {   // 16 rows x 64 = 256 float4, one per thread
        int row = t >> 4, k4 = (t & 15) << 2;
        float4 v = *reinterpret_cast<const float4*>(src_g + row * C_ + k4);
        XA[row][k4 + 0] = v.x; XA[row][k4 + 1] = v.y;
        XA[row][k4 + 2] = v.z; XA[row][k4 + 3] = v.w;
    }

    const float* Ws[4] = {w1, w2, w3, pw1};
    const float* Bs[4] = {b1, b2, b3, nullptr};

    float (*sA)[C_ + 1] = XA;
    float (*sB)[C_ + 1] = XB;

    for (int layer = 0; layer < 4; ++layer) {
        __syncthreads();
        for (int e = t; e < C_ * C_ / 4; e += 256)
            reinterpret_cast<float4*>(W)[e] =
                reinterpret_cast<const float4*>(Ws[layer])[e];
        if (t < C_) Bv[t] = (layer == 3) ? 0.0f : Bs[layer][t];
        __syncthreads();
        const bool relu = (layer < 2);
        #pragma unroll
        for (int q = 0; q < 4; ++q) {
            const int row = rg * 4 + q;
            float acc = Bv[c];
            #pragma unroll 8
            for (int k = 0; k < C_; ++k)
                acc = fmaf(sA[row][k], W[k * C_ + c], acc);
            sB[row][c] = relu ? fmaxf(acc, 0.0f) : acc;
        }
        float (*tmp)[C_ + 1] = sA; sA = sB; sB = tmp;
    }
    #pragma unroll
    for (int q = 0; q < 4; ++q) {
        const int row = rg * 4 + q;
        U[(size_t)(rbase + row) * C_ + c] = sA[row][c];
    }
}

// ---------------------------------------------------------------------------
// Kernel 2: pairwise post-MLP via single-f16 MFMA + fused column top-2 (zz=1).
// Transposed GEMM: D[ch][pair] = W2^T (A) x H1^T (B).
// Block: 32 i x 32 j, 4 waves (wave = 16i x 16j quadrant).
// ---------------------------------------------------------------------------
__global__ __launch_bounds__(256) void pair_kernel(
    const float* __restrict__ U,
    const _Float16* __restrict__ w2T,
    const float* __restrict__ pb1, const float* __restrict__ pb2,
    const float* __restrict__ pw3, const float* __restrict__ pb3,
    float* __restrict__ out, unsigned long long* __restrict__ PT2)
{
    __shared__ float SU[32][68];
    __shared__ float SVB[32][68];
    __shared__ float OUTT[32][33][2];
    __shared__ unsigned long long RED[8][32][2];

    const int t = threadIdx.x;
    const int lane = t & 63;
    const int wave = t >> 6;
    const int wi = wave >> 1, wj = wave & 1;
    const int zz = blockIdx.z;
    const int ibase = blockIdx.y * 32;
    const int jbase = blockIdx.x * 32;

    {   // stage SU (U rows) and SVB (V rows + post_b1): 8 f32 per thread each
        int r = t >> 3, k0 = (t & 7) * 8;
        const float* up = U + (size_t)(ibase + r) * C_ + k0;
        *reinterpret_cast<float4*>(&SU[r][k0])     = *reinterpret_cast<const float4*>(up);
        *reinterpret_cast<float4*>(&SU[r][k0 + 4]) = *reinterpret_cast<const float4*>(up + 4);
        const float* vp = U + (size_t)((zz ? N_ : 0) + jbase + r) * C_ + k0;
        float4 b0 = *reinterpret_cast<const float4*>(vp);
        float4 b1v = *reinterpret_cast<const float4*>(vp + 4);
        float4 c0 = *reinterpret_cast<const float4*>(pb1 + k0);
        float4 c1 = *reinterpret_cast<const float4*>(pb1 + k0 + 4);
        b0.x += c0.x; b0.y += c0.y; b0.z += c0.z; b0.w += c0.w;
        b1v.x += c1.x; b1v.y += c1.y; b1v.z += c1.z; b1v.w += c1.w;
        *reinterpret_cast<float4*>(&SVB[r][k0])     = b0;
        *reinterpret_cast<float4*>(&SVB[r][k0 + 4]) = b1v;
    }

    const int ch_l = lane & 15;   // A row (channel) within tile / B col (pair)
    const int kg = lane >> 4;     // k-group

    // A-frags: W2^T, lane holds A[row=mt*16+ch_l][k = ks*32 + kg*8 + e]
    f16x8 whi[4][2];
    #pragma unroll
    for (int mt = 0; mt < 4; ++mt)
        #pragma unroll
        for (int ks = 0; ks < 2; ++ks)
            whi[mt][ks] = *reinterpret_cast<const f16x8*>(
                w2T + (mt * 16 + ch_l) * 64 + ks * 32 + kg * 8);

    // per-lane b2 / w3 for D rows ch = mt*16 + kg*4 + r
    float b2v[16], w30[16], w31[16];
    #pragma unroll
    for (int mt = 0; mt < 4; ++mt)
        #pragma unroll
        for (int r = 0; r < 4; ++r) {
            int ch = mt * 16 + kg * 4 + r;
            b2v[mt * 4 + r] = pb2[ch];
            w30[mt * 4 + r] = pw3[ch * 2];
            w31[mt * 4 + r] = pw3[ch * 2 + 1];
        }
    const float ob0 = pb3[0], ob1 = pb3[1];

    __syncthreads();

    // hoist su: this lane's pair row is i = wi*16 + ch_l
    float su[2][8];
    #pragma unroll
    for (int ks = 0; ks < 2; ++ks) {
        int k0 = ks * 32 + kg * 8;
        float4 a = *reinterpret_cast<const float4*>(&SU[wi * 16 + ch_l][k0]);
        float4 b = *reinterpret_cast<const float4*>(&SU[wi * 16 + ch_l][k0 + 4]);
        su[ks][0] = a.x; su[ks][1] = a.y; su[ks][2] = a.z; su[ks][3] = a.w;
        su[ks][4] = b.x; su[ks][5] = b.y; su[ks][6] = b.z; su[ks][7] = b.w;
    }

    for (int jj = 0; jj < 16; ++jj) {
        const int jr = wj * 16 + jj;
        f16x8 bhi[2];
        #pragma unroll
        for (int ks = 0; ks < 2; ++ks) {
            int k0 = ks * 32 + kg * 8;
            float4 a = *reinterpret_cast<const float4*>(&SVB[jr][k0]);      // broadcast
            float4 b = *reinterpret_cast<const float4*>(&SVB[jr][k0 + 4]);
            float sv[8] = {a.x, a.y, a.z, a.w, b.x, b.y, b.z, b.w};
            union { f16x8 v; fp16x2 h2[4]; } bu;
            #pragma unroll
            for (int m = 0; m < 4; ++m) {
                float x0 = fmaxf(su[ks][2 * m]     + sv[2 * m],     0.0f);
                float x1 = fmaxf(su[ks][2 * m + 1] + sv[2 * m + 1], 0.0f);
                bu.h2[m] = __builtin_amdgcn_cvt_pkrtz(x0, x1);  // packed f32->2xf16
            }
            bhi[ks] = bu.v;
        }
        f32x4 ah[4];
        #pragma unroll
        for (int mt = 0; mt < 4; ++mt)
            ah[mt] = f32x4{b2v[4 * mt], b2v[4 * mt + 1], b2v[4 * mt + 2], b2v[4 * mt + 3]};
        #pragma unroll
        for (int ks = 0; ks < 2; ++ks)
            #pragma unroll
            for (int mt = 0; mt < 4; ++mt)
                ah[mt] = __builtin_amdgcn_mfma_f32_16x16x32_f16(whi[mt][ks], bhi[ks], ah[mt], 0, 0, 0);
        // epilogue: h2 = relu(acc) (b2 folded into init); layer3 dot
        float p0 = 0.0f, p1 = 0.0f;
        #pragma unroll
        for (int mt = 0; mt < 4; ++mt)
            #pragma unroll
            for (int r = 0; r < 4; ++r) {
                float g = fmaxf(ah[mt][r], 0.0f);
                p0 = fmaf(g, w30[4 * mt + r], p0);
                p1 = fmaf(g, w31[4 * mt + r], p1);
            }
        // reduce over the 4 kg groups (each lane holds 16 of 64 channels)
        p0 += __shfl_xor(p0, 16); p0 += __shfl_xor(p0, 32);
        p1 += __shfl_xor(p1, 16); p1 += __shfl_xor(p1, 32);
        if (lane < 16) {
            OUTT[wi * 16 + lane][wj * 16 + jj][0] = p0 + ob0;
            OUTT[wi * 16 + lane][wj * 16 + jj][1] = p1 + ob1;
        }
    }
    __syncthreads();
    {   // write out
        float* obase = out + (size_t)zz * (2ull * N_ * M_);
        int r = t >> 3;
        int q0 = (t & 7) * 4;
        int i = ibase + r;
        #pragma unroll
        for (int q = 0; q < 4; ++q) {
            int j = jbase + q0 + q;
            float2 v = *reinterpret_cast<float2*>(&OUTT[r][q0 + q][0]);
            *reinterpret_cast<float2*>(obase + ((size_t)i * M_ + j) * 2) = v;
        }
    }
    if (zz) {   // fused column top-2 over this block's 32 rows (logit [...,0])
        const int tc = t & 31, tg = t >> 5;
        unsigned long long k1 = 0, k2 = 0;
        #pragma unroll
        for (int q = 0; q < 4; ++q) {
            int r = tg * 4 + q;
            unsigned long long k = packlogit(OUTT[r][tc][0], (unsigned)(ibase + r));
            if (k > k1) { k2 = k1; k1 = k; } else if (k > k2) k2 = k;
        }
        RED[tg][tc][0] = k1; RED[tg][tc][1] = k2;
        for (int h = 4; h > 0; h >>= 1) {
            __syncthreads();
            if (tg < h) {
                unsigned long long a = RED[tg + h][tc][0], b = RED[tg + h][tc][1];
                if (a > k1) { k2 = k1; k1 = a; } else if (a > k2) k2 = a;
                if (b > k1) { k2 = k1; k1 = b; } else if (b > k2) k2 = b;
                RED[tg][tc][0] = k1; RED[tg][tc][1] = k2;
            }
        }
        if (tg == 0) {
            size_t o = ((size_t)blockIdx.y * M_ + (jbase + tc)) * 2;
            PT2[o] = k1; PT2[o + 1] = k2;
        }
    }
}

// ---------------------------------------------------------------------------
// Kernel 3: per-column final: merge 32-chunk top-2 (wave butterfly), near-tie
// exact f32 recompute, exact sigmoid value, row-argmax atomic. 1 wave/column.
// ---------------------------------------------------------------------------
__global__ __launch_bounds__(64) void colfinal_kernel(
    const unsigned long long* __restrict__ PT2,
    const float* __restrict__ U, const float* __restrict__ pb1,
    const float* __restrict__ pw2, const float* __restrict__ pb2,
    const float* __restrict__ pw3, const float* __restrict__ pb3,
    unsigned long long* __restrict__ rowbest)
{
    __shared__ float h1s[64];
    const int j = blockIdx.x;
    const int lane = threadIdx.x;

    // lane (ic*2+e) loads PT2[ic][j][e]; butterfly-merge top-2 across wave
    unsigned long long k1 = PT2[((size_t)(lane >> 1) * M_ + j) * 2 + (lane & 1)];
    unsigned long long k2 = 0;
    #pragma unroll
    for (int m = 1; m < 64; m <<= 1) {
        unsigned long long a = shflx64(k1, m), b = shflx64(k2, m);
        if (a > k1) { k2 = k1; k1 = a; } else if (a > k2) k2 = a;
        if (b > k1) { k2 = k1; k1 = b; } else if (b > k2) k2 = b;
    }
    // all lanes now hold the global top-2 for column j
    int ids[2];
    ids[0] = (int)(0xFFFFFFFFu - (unsigned)(k1 & 0xFFFFFFFFull));
    ids[1] = (int)(0xFFFFFFFFu - (unsigned)(k2 & 0xFFFFFFFFull));
    float v1 = unflipbits((unsigned)(k1 >> 32));
    float v2 = unflipbits((unsigned)(k2 >> 32));
    const int nc = (v1 - v2 < 8e-3f) ? 2 : 1;   // false on NaN (k2==0) -> nc=1

    float logits[2] = {0.0f, 0.0f};
    for (int cnd = 0; cnd < nc; ++cnd) {
        int i = ids[cnd];
        h1s[lane] = fmaxf(U[(size_t)i * C_ + lane] + U[(size_t)(N_ + j) * C_ + lane] + pb1[lane], 0.0f);
        __syncthreads();
        float acc = pb2[lane];
        #pragma unroll 8
        for (int k = 0; k < 64; ++k)
            acc = fmaf(h1s[k], pw2[k * 64 + lane], acc);
        float p = fmaxf(acc, 0.0f) * pw3[lane * 2];
        #pragma unroll
        for (int m = 1; m < 64; m <<= 1) p += __shfl_xor(p, m);
        logits[cnd] = p + pb3[0];
        __syncthreads();
    }
    int wi; float wp;
    if (nc == 1) { wi = ids[0]; wp = logits[0]; }
    else if (logits[0] > logits[1]) { wi = ids[0]; wp = logits[0]; }
    else if (logits[1] > logits[0]) { wi = ids[1]; wp = logits[1]; }
    else { wi = min(ids[0], ids[1]); wp = logits[0]; }
    if (lane == 0)
        atomicMax(&rowbest[wi], packpos(sig(wp), (unsigned)j));
}

// ---------------------------------------------------------------------------
// Kernel 4: zero matched row + scatter that row's mutual match (if any).
// ---------------------------------------------------------------------------
__global__ __launch_bounds__(256) void zscatter_kernel(
    const unsigned long long* __restrict__ rowbest, float* __restrict__ matched)
{
    int i = blockIdx.x;
    int t = threadIdx.x;
    *reinterpret_cast<float4*>(matched + (size_t)i * M_ + t * 4) =
        float4{0.0f, 0.0f, 0.0f, 0.0f};
    __syncthreads();
    if (t == 0) {
        unsigned long long key = rowbest[i];
        if (key) {
            unsigned j = 0xFFFFFFFFu - (unsigned)(key & 0xFFFFFFFFull);
            matched[(size_t)i * M_ + j] = __uint_as_float((unsigned)(key >> 32));
        }
    }
}

} // namespace

extern "C" void kernel_launch(void* const* d_in, const int* in_sizes, int n_in,
                              void* d_out, int out_size, void* d_ws, size_t ws_size,
                              hipStream_t stream)
{
    const float* step_x  = (const float*)d_in[0];
    const float* state_x = (const float*)d_in[1];
    const float* pre_w1  = (const float*)d_in[2];
    const float* pre_b1  = (const float*)d_in[3];
    const float* pre_w2  = (const float*)d_in[4];
    const float* pre_b2  = (const float*)d_in[5];
    const float* pre_w3  = (const float*)d_in[6];
    const float* pre_b3  = (const float*)d_in[7];
    const float* post_w1 = (const float*)d_in[8];
    const float* post_b1 = (const float*)d_in[9];
    const float* post_w2 = (const float*)d_in[10];
    const float* post_b2 = (const float*)d_in[11];
    const float* post_w3 = (const float*)d_in[12];
    const float* post_b3 = (const float*)d_in[13];

    float* out     = (float*)d_out;
    float* matched = out + 4ull * N_ * M_;

    // ws: U (512KB) + rowbest (8KB)
    float* U = (float*)d_ws;
    unsigned long long* rowbest = (unsigned long long*)((char*)d_ws + 2048ull * 64 * 4);

    // scratch inside 'matched' (4MB), all consumed before zscatter rewrites it:
    char* ms = (char*)matched;
    unsigned long long* PT2 = (unsigned long long*)ms;            // 512KB (pair->colfinal)
    _Float16*  w2T     = (_Float16*)(ms + 512 * 1024);            // 8KB (pre->pair)

    hipLaunchKernelGGL(pre_prep_kernel, dim3(129), dim3(256), 0, stream,
        step_x, state_x, pre_w1, pre_b1, pre_w2, pre_b2, pre_w3, pre_b3,
        post_w1, post_w2, U, w2T, rowbest);
    hipLaunchKernelGGL(pair_kernel, dim3(32, 32, 2), dim3(256), 0, stream,
        U, w2T, post_b1, post_b2, post_w3, post_b3, out, PT2);
    hipLaunchKernelGGL(colfinal_kernel, dim3(1024), dim3(64), 0, stream,
        PT2, U, post_b1, post_w2, post_b2, post_w3, post_b3, rowbest);
    hipLaunchKernelGGL(zscatter_kernel, dim3(1024), dim3(256), 0, stream,
        rowbest, matched);
}